// Round 11
// baseline (785.986 us; speedup 1.0000x reference)
//
#include <hip/hip_runtime.h>

typedef unsigned short u16;
typedef unsigned int u32;

using short8 = __attribute__((ext_vector_type(8))) short;
using f32x4  = __attribute__((ext_vector_type(4))) float;

#define LOG2E 1.44269504088896340736f

// X1 row (per batch): [h1_hi 0:128 | h1_lo 128:256 | x 256:272 | zeros 272:288 | pad]
#define X1S 296
// H2 row: [h2_hi 0:64 | h2_lo 64:128 | pad]
#define H2S 136
#define DBS 40

__device__ __forceinline__ u16 f2bf(float f) {
  u32 u = __float_as_uint(f);
  return (u16)((u + 0x7FFFu + ((u >> 16) & 1u)) >> 16);
}
__device__ __forceinline__ f32x4 sigm4(f32x4 x) {
  f32x4 m = x * (-LOG2E);
  f32x4 e;
  #pragma unroll
  for (int i = 0; i < 4; i++) e[i] = __builtin_amdgcn_exp2f(m[i]);
  e = e + 1.0f;
  f32x4 r;
  #pragma unroll
  for (int i = 0; i < 4; i++) r[i] = __builtin_amdgcn_rcpf(e[i]);
  return r;
}
__device__ __forceinline__ f32x4 tanh4(f32x4 x) {
  f32x4 m = x * (2.0f * LOG2E);
  f32x4 e;
  #pragma unroll
  for (int i = 0; i < 4; i++) e[i] = __builtin_amdgcn_exp2f(m[i]);
  e = e + 1.0f;
  f32x4 r;
  #pragma unroll
  for (int i = 0; i < 4; i++) r[i] = __builtin_amdgcn_rcpf(e[i]);
  return r * (-2.0f) + 1.0f;
}
__device__ __forceinline__ f32x4 mfma_(short8 a, short8 b, f32x4 c) {
  return __builtin_amdgcn_mfma_f32_16x16x32_bf16(a, b, c, 0, 0, 0);
}

// 512 threads, 8 waves (2/SIMD), 1 block/CU. Balanced split:
//   waves 4-7 (A): TWO L1 tile-sets each (72 MFMA, 8 acc chains)
//   waves 0-3 (B): all of L2 (48 MFMA, 8 chains hi/lo-split) + x staging + head
// Encoder: ONE barrier per step (waves self-stagger between it).
__global__ __launch_bounds__(512, 1) void spc_lstm(
    const float* __restrict__ xh,   const float* __restrict__ xfr,
    const float* __restrict__ Wih1, const float* __restrict__ Whh1,
    const float* __restrict__ bih1, const float* __restrict__ bhh1,
    const float* __restrict__ Wih2, const float* __restrict__ Whh2,
    const float* __restrict__ bih2, const float* __restrict__ bhh2,
    const float* __restrict__ Wd,   const float* __restrict__ bd,
    const float* __restrict__ Wf,   const float* __restrict__ bfv,
    const float* __restrict__ ob,   float* __restrict__ out)
{
  __shared__ __align__(16) u16 X1[2][16 * X1S];   // 18944 B
  __shared__ __align__(16) u16 H2B[2][16 * H2S];  //  8704 B
  __shared__ __align__(16) u16 DB[16 * DBS];      //  1280 B
  __shared__ __align__(16) u16 W1xF[32 * 256];    // 16384 B Wih1 x-frags (k<16)
  __shared__ __align__(16) u16 W2F[64 * 512];     // 65536 B Wih2 frags
  __shared__ __align__(16) u16 WdF[4 * 512];      //  4096 B
  __shared__ __align__(16) u16 WfF[512];          //  1024 B
  __shared__ u16 PREDV[16][2];

  const int tid = threadIdx.x;
  const int wv  = tid >> 6;          // 0..7
  const int l   = tid & 63;
  const int c   = l & 15;
  const int q   = l >> 4;
  const int bb  = blockIdx.x << 4;
  const bool isB = (wv < 4);         // B: L2 + staging + head
  const int wb  = wv;                // B id (0..3)
  const int wa  = wv - 4;            // A id (0..3), owns L1 unit-tiles 2wa, 2wa+1

  // role-overlaid weight registers:
  //   A: wreg[s][ty][kc] = Whh1 frags for tile s (128 VGPR)
  //   B: wreg[0][ty][0..1] = Whh2 frags (32 VGPR)
  short8 wreg[2][4][4];
  float  br[2][4];                   // A: b1 per tile; B: b2 in br[0]
  f32x4  cst[2];                     // A: c1 per tile; B: c2 in cst[0]
  cst[0] = (f32x4){0,0,0,0}; cst[1] = (f32x4){0,0,0,0};

  // ---- zero activation LDS ----
  for (int i = tid; i < 2 * 16 * X1S; i += 512) ((u16*)X1)[i] = 0;
  for (int i = tid; i < 2 * 16 * H2S; i += 512) ((u16*)H2B)[i] = 0;
  for (int i = tid; i < 16 * DBS; i += 512) DB[i] = 0;
  if (tid < 32) ((u16*)PREDV)[tid] = 0;
  __syncthreads();

  // ---- weight LDS fills (fragment-linear: (k,n) -> ((k>>3)*16+n)*8 + (k&7)) ----
  for (int i = tid; i < 64 * 512; i += 512) {         // Wih2 tiles (ww, ty, kc)
    const int rid = i >> 9, e = i & 511, k = e >> 4, n = e & 15;
    const int ww = rid >> 4, ty = (rid >> 2) & 3, kc = rid & 3;
    const int g = ty * 64 + ww * 16 + n;
    W2F[rid * 512 + ((k >> 3) * 16 + n) * 8 + (k & 7)] = f2bf(Wih2[g * 128 + kc * 32 + k]);
  }
  for (int i = tid; i < 32 * 256; i += 512) {         // Wih1 x-frags, tiles T = ty*8+uv
    const int T = i >> 8, e = i & 255, k = e >> 4, n = e & 15;
    const int ty = T >> 3, uv = T & 7;
    const int g = ty * 128 + uv * 16 + n;
    W1xF[T * 256 + ((k >> 3) * 16 + n) * 8 + (k & 7)] = f2bf(Wih1[g * 16 + k]);
  }
  for (int i = tid; i < 4 * 512; i += 512) {          // Wd tiles (ww, kc2)
    const int tix = i >> 9, e = i & 511, k = e >> 4, n = e & 15;
    const int ww = tix >> 1, kc2 = tix & 1;
    WdF[tix * 512 + ((k >> 3) * 16 + n) * 8 + (k & 7)] =
        f2bf(Wd[(ww * 16 + n) * 64 + kc2 * 32 + k]);
  }
  for (int i = tid; i < 512; i += 512) {              // Wf (zeros n>=2)
    const int k = i >> 4, n = i & 15;
    WfF[((k >> 3) * 16 + n) * 8 + (k & 7)] = (n < 2) ? f2bf(Wf[n * 32 + k]) : (u16)0;
  }

  // ---- register weights / biases ----
  if (!isB) {
    #pragma unroll
    for (int s = 0; s < 2; s++) {
      const int uv = wa * 2 + s;
      #pragma unroll
      for (int ty = 0; ty < 4; ty++) {
        const int g = ty * 128 + uv * 16 + c;
        br[s][ty] = bih1[g] + bhh1[g];
        #pragma unroll
        for (int kc = 0; kc < 4; kc++) {
          short8 v;
          #pragma unroll
          for (int j = 0; j < 8; j++)
            v[j] = (short)f2bf(Whh1[g * 128 + kc * 32 + q * 8 + j]);
          wreg[s][ty][kc] = v;
        }
      }
    }
  } else {
    #pragma unroll
    for (int ty = 0; ty < 4; ty++) {
      const int g2 = ty * 64 + wb * 16 + c;
      br[0][ty] = bih2[g2] + bhh2[g2];
      #pragma unroll
      for (int kc = 0; kc < 2; kc++) {
        short8 v;
        #pragma unroll
        for (int j = 0; j < 8; j++)
          v[j] = (short)f2bf(Whh2[g2 * 64 + kc * 32 + q * 8 + j]);
        wreg[0][ty][kc] = v;
      }
    }
  }
  const float bdr = (isB && wb < 2) ? bd[wb * 16 + c] : 0.f;
  const float bfr = (isB && wb == 0 && c < 2) ? (bfv[c] + ob[c]) : 0.f;

  // ---- x staging (B waves = tid<256): stage x(0), prime x(1) ----
  const int xr = (tid >> 4) & 15, xcc = tid & 15;
  float xreg = 0.f; bool dreg = false;
  if (isB) {
    X1[0][xr * X1S + 256 + xcc] = f2bf(xh[(bb + xr) * 3200 + xcc]);
    xreg = xh[(bb + xr) * 3200 + 16 + xcc]; dreg = true;
  }
  __syncthreads();

  for (int t = 0; t <= 220; t++) {
    u16* Xc    = X1[t & 1];        // h1(t-1) hi/lo + x(t)
    u16* Xn    = X1[(t + 1) & 1];  // h1(t) dest, x(t+1) stage
    u16* Hprev = H2B[t & 1];       // h2(t-2)
    u16* Hdst  = H2B[(t + 1) & 1]; // h2(t-1) dest
    const bool dec  = (t >= 201);
    const bool doL1 = !isB && (t <= 219);
    const bool doL2 = isB && (t >= 1);

    // ==== A: issue L1(t) MFMAs (h-part always; x-part in encoder) ====
    f32x4 acc1[2][4];
    if (doL1) {
      #pragma unroll
      for (int s = 0; s < 2; s++)
        #pragma unroll
        for (int ty = 0; ty < 4; ty++)
          acc1[s][ty] = (f32x4){br[s][ty], br[s][ty], br[s][ty], br[s][ty]};
      short8 fh[4];
      #pragma unroll
      for (int kc = 0; kc < 4; kc++)
        fh[kc] = *(const short8*)&Xc[c * X1S + kc * 32 + q * 8];
      #pragma unroll
      for (int kc = 0; kc < 4; kc++)
        #pragma unroll
        for (int s = 0; s < 2; s++)
          #pragma unroll
          for (int ty = 0; ty < 4; ty++)
            acc1[s][ty] = mfma_(fh[kc], wreg[s][ty][kc], acc1[s][ty]);
      #pragma unroll
      for (int kc = 0; kc < 4; kc++)
        fh[kc] = *(const short8*)&Xc[c * X1S + 128 + kc * 32 + q * 8];
      #pragma unroll
      for (int kc = 0; kc < 4; kc++)
        #pragma unroll
        for (int s = 0; s < 2; s++)
          #pragma unroll
          for (int ty = 0; ty < 4; ty++)
            acc1[s][ty] = mfma_(fh[kc], wreg[s][ty][kc], acc1[s][ty]);
      if (t <= 200) {
        const short8 ax = *(const short8*)&Xc[c * X1S + 256 + q * 8];
        #pragma unroll
        for (int s = 0; s < 2; s++)
          #pragma unroll
          for (int ty = 0; ty < 4; ty++) {
            short8 wxv = (short8){0,0,0,0,0,0,0,0};
            if (q < 2) wxv = *(const short8*)&W1xF[(ty * 8 + wa * 2 + s) * 256 + l * 8];
            acc1[s][ty] = mfma_(ax, wxv, acc1[s][ty]);
          }
      }
    }

    // ==== B: L2(t-1) issue (hi/lo chain-split) + elem ====
    if (doL2) {
      f32x4 a2a[4], a2b[4];
      #pragma unroll
      for (int ty = 0; ty < 4; ty++) {
        a2a[ty] = (f32x4){br[0][ty], br[0][ty], br[0][ty], br[0][ty]};
        a2b[ty] = (f32x4){0, 0, 0, 0};
      }
      short8 fh[4];
      #pragma unroll
      for (int kc = 0; kc < 4; kc++)
        fh[kc] = *(const short8*)&Xc[c * X1S + kc * 32 + q * 8];
      #pragma unroll
      for (int kc = 0; kc < 4; kc++)
        #pragma unroll
        for (int ty = 0; ty < 4; ty++)
          a2a[ty] = mfma_(fh[kc], *(const short8*)&W2F[(wb * 16 + ty * 4 + kc) * 512 + l * 8], a2a[ty]);
      #pragma unroll
      for (int kc = 0; kc < 2; kc++) {
        const short8 hhi = *(const short8*)&Hprev[c * H2S + kc * 32 + q * 8];
        #pragma unroll
        for (int ty = 0; ty < 4; ty++)
          a2a[ty] = mfma_(hhi, wreg[0][ty][kc], a2a[ty]);
      }
      #pragma unroll
      for (int kc = 0; kc < 4; kc++)
        fh[kc] = *(const short8*)&Xc[c * X1S + 128 + kc * 32 + q * 8];
      #pragma unroll
      for (int kc = 0; kc < 4; kc++)
        #pragma unroll
        for (int ty = 0; ty < 4; ty++)
          a2b[ty] = mfma_(fh[kc], *(const short8*)&W2F[(wb * 16 + ty * 4 + kc) * 512 + l * 8], a2b[ty]);
      #pragma unroll
      for (int kc = 0; kc < 2; kc++) {
        const short8 hlo = *(const short8*)&Hprev[c * H2S + 64 + kc * 32 + q * 8];
        #pragma unroll
        for (int ty = 0; ty < 4; ty++)
          a2b[ty] = mfma_(hlo, wreg[0][ty][kc], a2b[ty]);
      }
      // elem (packed) -> h2(t-1)
      f32x4 ig = sigm4(a2a[0] + a2b[0]);
      f32x4 fg = sigm4(a2a[1] + a2b[1]);
      f32x4 gg = tanh4(a2a[2] + a2b[2]);
      f32x4 og = sigm4(a2a[3] + a2b[3]);
      f32x4 cn = fg * cst[0] + ig * gg;
      f32x4 hn = og * tanh4(cn);
      cst[0] = cn;
      const int u2 = wb * 16 + c;
      #pragma unroll
      for (int r = 0; r < 4; r++) {
        u32 uu = __float_as_uint(hn[r]);
        float lo = hn[r] - __uint_as_float(uu & 0xFFFF0000u);
        const int row = (q * 4 + r) * H2S;
        Hdst[row + u2]      = (u16)(uu >> 16);
        Hdst[row + 64 + u2] = (u16)(__float_as_uint(lo) >> 16);
      }
    }

    // ==== decoder head (A-waves wait here with MFMAs in flight) ====
    if (dec) {
      __syncthreads();                 // #1: h2(t-1) visible
      if (isB && wb < 2) {
        f32x4 accd = (f32x4){bdr, bdr, bdr, bdr};
        #pragma unroll
        for (int kc = 0; kc < 4; kc++) {
          const short8 ad  = *(const short8*)&Hdst[c * H2S + kc * 32 + q * 8];
          const short8 wdk = *(const short8*)&WdF[(wb * 2 + (kc & 1)) * 512 + l * 8];
          accd = mfma_(ad, wdk, accd);
        }
        #pragma unroll
        for (int r = 0; r < 4; r++)
          DB[(q * 4 + r) * DBS + wb * 16 + c] = f2bf(fmaxf(accd[r], 0.f));
      }
      __syncthreads();                 // #2: d visible
      if (isB && wb == 0) {
        const short8 ap  = *(const short8*)&DB[c * DBS + q * 8];
        const short8 wfv = *(const short8*)&WfF[l * 8];
        f32x4 accp = (f32x4){bfr, bfr, bfr, bfr};
        accp = mfma_(ap, wfv, accp);
        if (c < 2) {
          #pragma unroll
          for (int r = 0; r < 4; r++) {
            const int b = q * 4 + r;
            out[(bb + b) * 40 + (t - 201) * 2 + c] = accp[r];
            PREDV[b][c] = f2bf(accp[r]);
          }
        }
      }
      __syncthreads();                 // #3: pred visible
      if (doL1) {                      // deferred x-part with pred feedback
        short8 ax = *(const short8*)&Xc[c * X1S + 256 + q * 8];
        if (q == 1) {
          ax[6] = (short)PREDV[c][0];
          ax[7] = (short)PREDV[c][1];
        }
        #pragma unroll
        for (int s = 0; s < 2; s++)
          #pragma unroll
          for (int ty = 0; ty < 4; ty++) {
            short8 wxv = (short8){0,0,0,0,0,0,0,0};
            if (q < 2) wxv = *(const short8*)&W1xF[(ty * 8 + wa * 2 + s) * 256 + l * 8];
            acc1[s][ty] = mfma_(ax, wxv, acc1[s][ty]);
          }
      }
    }

    // ==== A: L1 elem (both tiles, packed) -> h1(t) ====
    if (doL1) {
      #pragma unroll
      for (int s = 0; s < 2; s++) {
        f32x4 ig = sigm4(acc1[s][0]);
        f32x4 fg = sigm4(acc1[s][1]);
        f32x4 gg = tanh4(acc1[s][2]);
        f32x4 og = sigm4(acc1[s][3]);
        f32x4 cn = fg * cst[s] + ig * gg;
        f32x4 hn = og * tanh4(cn);
        cst[s] = cn;
        const int u = (wa * 2 + s) * 16 + c;
        #pragma unroll
        for (int r = 0; r < 4; r++) {
          u32 uu = __float_as_uint(hn[r]);
          float lo = hn[r] - __uint_as_float(uu & 0xFFFF0000u);
          const int row = (q * 4 + r) * X1S;
          Xn[row + u]       = (u16)(uu >> 16);
          Xn[row + 128 + u] = (u16)(__float_as_uint(lo) >> 16);
        }
      }
    }

    // ==== B: stage x(t+1), prefetch x(t+2) ====
    if (isB) {
      const float xw = xreg; const bool dw = dreg;
      const int s2 = t + 2;
      dreg = false;
      if (s2 < 200) { xreg = xh[(bb + xr) * 3200 + s2 * 16 + xcc]; dreg = true; }
      else if (s2 < 220) {
        const int s = s2 - 200;
        if (xcc < 14)    { xreg = xfr[(bb + xr) * 280 + s * 14 + xcc]; dreg = true; }
        else if (s == 0) { xreg = xh[(bb + xr) * 3200 + 199 * 16 + xcc]; dreg = true; }
      }
      if (dw) Xn[xr * X1S + 256 + xcc] = f2bf(xw);
    }
    __syncthreads();                   // end: h1(t), h2(t-1), x(t+1) published
  }
}

extern "C" void kernel_launch(void* const* d_in, const int* in_sizes, int n_in,
                              void* d_out, int out_size, void* d_ws, size_t ws_size,
                              hipStream_t stream) {
  (void)in_sizes; (void)n_in; (void)out_size; (void)d_ws; (void)ws_size;
  spc_lstm<<<dim3(256), dim3(512), 0, stream>>>(
      (const float*)d_in[0],  (const float*)d_in[1],
      (const float*)d_in[2],  (const float*)d_in[3],
      (const float*)d_in[4],  (const float*)d_in[5],
      (const float*)d_in[6],  (const float*)d_in[7],
      (const float*)d_in[8],  (const float*)d_in[9],
      (const float*)d_in[10], (const float*)d_in[11],
      (const float*)d_in[12], (const float*)d_in[13],
      (const float*)d_in[14], (float*)d_out);
}

// Round 12
// 468.885 us; speedup vs baseline: 1.6763x; 1.6763x over previous
//
#include <hip/hip_runtime.h>

typedef unsigned short u16;
typedef unsigned int u32;

using short8 = __attribute__((ext_vector_type(8))) short;
using f32x4  = __attribute__((ext_vector_type(4))) float;

#define LOG2E 1.44269504088896340736f

// X1 row (per batch): [h1 0:128 | x 128:144 | zeros 144:160 | pad] (u16 units)
#define X1S 168
// H2 row: [h2 0:64 | pad]
#define H2S 72
#define DBS 40

__device__ __forceinline__ u16 f2bf(float f) {
  u32 u = __float_as_uint(f);
  return (u16)((u + 0x7FFFu + ((u >> 16) & 1u)) >> 16);
}
__device__ __forceinline__ float sigm(float x) {
  return __builtin_amdgcn_rcpf(1.0f + __builtin_amdgcn_exp2f(-LOG2E * x));
}
__device__ __forceinline__ float tanh_(float x) {
  return 1.0f - 2.0f * __builtin_amdgcn_rcpf(1.0f + __builtin_amdgcn_exp2f(2.0f * LOG2E * x));
}
__device__ __forceinline__ f32x4 mfma_(short8 a, short8 b, f32x4 c) {
  return __builtin_amdgcn_mfma_f32_16x16x32_bf16(a, b, c, 0, 0, 0);
}

// R12 = R7 structure (best measured: 2 waves/SIMD, 1-barrier encoder,
// waves 0-3 = L1+L2, waves 4-7 = L1 + x-staging + head) MINUS the hi/lo
// activation compensation: h1/h2 stored as single bf16 (rounded), halving
// MFMA count (120 -> 64 per SIMD-pair), activation LDS traffic, and the
// elem pack/store work. c-states stay fp32 in registers.
__global__ __launch_bounds__(512, 1) void spc_lstm(
    const float* __restrict__ xh,   const float* __restrict__ xfr,
    const float* __restrict__ Wih1, const float* __restrict__ Whh1,
    const float* __restrict__ bih1, const float* __restrict__ bhh1,
    const float* __restrict__ Wih2, const float* __restrict__ Whh2,
    const float* __restrict__ bih2, const float* __restrict__ bhh2,
    const float* __restrict__ Wd,   const float* __restrict__ bd,
    const float* __restrict__ Wf,   const float* __restrict__ bfv,
    const float* __restrict__ ob,   float* __restrict__ out)
{
  __shared__ __align__(16) u16 X1[2][16 * X1S];   // 10752 B
  __shared__ __align__(16) u16 H2B[2][16 * H2S];  //  4608 B
  __shared__ __align__(16) u16 DB[16 * DBS];      //  1280 B
  __shared__ __align__(16) u16 W1xF[32 * 256];    // 16384 B (k<16 only)
  __shared__ __align__(16) u16 W2F[64 * 512];     // 65536 B Wih2
  __shared__ __align__(16) u16 WdF[4 * 512];      //  4096 B
  __shared__ __align__(16) u16 WfF[512];          //  1024 B
  __shared__ u16 PREDV[16][2];
  // ~104 KB

  const int tid = threadIdx.x;
  const int wv  = tid >> 6;          // 0..7
  const int l   = tid & 63;
  const int c   = l & 15;
  const int q   = l >> 4;
  const int bb  = blockIdx.x << 4;
  const bool isA = (wv < 4);         // waves 0-3: L1 + L2; waves 4-7: L1 + x + head

  short8 w1h[4][4];                  // Whh1 frags, 16 L1 units (64 VGPR)
  short8 w2h[4][2];                  // A only: Whh2 frags (32 VGPR)
  float  b1r[4];
  float  b2r[4] = {0.f, 0.f, 0.f, 0.f};

  // ---- zero activation LDS ----
  for (int i = tid; i < 2 * 16 * X1S; i += 512) ((u16*)X1)[i] = 0;
  for (int i = tid; i < 2 * 16 * H2S; i += 512) ((u16*)H2B)[i] = 0;
  for (int i = tid; i < 16 * DBS; i += 512) DB[i] = 0;
  if (tid < 32) ((u16*)PREDV)[tid] = 0;
  __syncthreads();

  // ---- weight LDS fills (fragment-linear: (k,n) -> ((k>>3)*16+n)*8 + (k&7)) ----
  for (int i = tid; i < 64 * 512; i += 512) {         // Wih2 tiles (ww, ty, kc)
    const int rid = i >> 9, e = i & 511, k = e >> 4, n = e & 15;
    const int ww = rid >> 4, ty = (rid >> 2) & 3, kc = rid & 3;
    const int g = ty * 64 + ww * 16 + n;
    W2F[rid * 512 + ((k >> 3) * 16 + n) * 8 + (k & 7)] = f2bf(Wih2[g * 128 + kc * 32 + k]);
  }
  for (int i = tid; i < 32 * 256; i += 512) {         // Wih1 x-frags, tiles T = ty*8+uv
    const int T = i >> 8, e = i & 255, k = e >> 4, n = e & 15;
    const int ty = T >> 3, uv = T & 7;
    const int g = ty * 128 + uv * 16 + n;
    W1xF[T * 256 + ((k >> 3) * 16 + n) * 8 + (k & 7)] = f2bf(Wih1[g * 16 + k]);
  }
  for (int i = tid; i < 4 * 512; i += 512) {          // Wd tiles (ww, kc2)
    const int tix = i >> 9, e = i & 511, k = e >> 4, n = e & 15;
    const int ww = tix >> 1, kc2 = tix & 1;
    WdF[tix * 512 + ((k >> 3) * 16 + n) * 8 + (k & 7)] =
        f2bf(Wd[(ww * 16 + n) * 64 + kc2 * 32 + k]);
  }
  {                                                   // Wf (zeros n>=2)
    const int k = tid >> 4, n = tid & 15;
    if (tid < 512)
      WfF[((k >> 3) * 16 + n) * 8 + (k & 7)] = (n < 2) ? f2bf(Wf[n * 32 + k]) : (u16)0;
  }

  // ---- register weights / biases (wave wv owns L1 units wv*16+c) ----
  #pragma unroll
  for (int ty = 0; ty < 4; ty++) {
    const int g = ty * 128 + wv * 16 + c;
    b1r[ty] = bih1[g] + bhh1[g];
    #pragma unroll
    for (int kc = 0; kc < 4; kc++) {
      short8 v;
      #pragma unroll
      for (int j = 0; j < 8; j++)
        v[j] = (short)f2bf(Whh1[g * 128 + kc * 32 + q * 8 + j]);
      w1h[ty][kc] = v;
    }
  }
  if (isA) {
    #pragma unroll
    for (int ty = 0; ty < 4; ty++) {
      const int g2 = ty * 64 + wv * 16 + c;
      b2r[ty] = bih2[g2] + bhh2[g2];
      #pragma unroll
      for (int kc = 0; kc < 2; kc++) {
        short8 v;
        #pragma unroll
        for (int j = 0; j < 8; j++)
          v[j] = (short)f2bf(Whh2[g2 * 64 + kc * 32 + q * 8 + j]);
        w2h[ty][kc] = v;
      }
    }
  }
  const float bdr = (wv == 4 || wv == 5) ? bd[(wv - 4) * 16 + c] : 0.f;
  const float bfr = (wv == 4 && c < 2) ? (bfv[c] + ob[c]) : 0.f;

  // ---- x staging (waves 4-7): stage x(0), prime x(1) ----
  const int xi = tid - 256, xr = (xi >> 4) & 15, xcc = xi & 15;
  float xreg = 0.f; bool dreg = false;
  if (!isA) {
    X1[0][xr * X1S + 128 + xcc] = f2bf(xh[(bb + xr) * 3200 + xcc]);
    xreg = xh[(bb + xr) * 3200 + 16 + xcc]; dreg = true;
  }
  f32x4 c1 = (f32x4){0,0,0,0};
  f32x4 c2 = (f32x4){0,0,0,0};
  __syncthreads();

  for (int t = 0; t <= 220; t++) {
    u16* Xc    = X1[t & 1];        // h1(t-1) + x(t)
    u16* Xn    = X1[(t + 1) & 1];  // h1(t) dest, x(t+1) stage
    u16* Hprev = H2B[t & 1];       // h2(t-2)
    u16* Hdst  = H2B[(t + 1) & 1]; // h2(t-1) dest
    const bool dec  = (t >= 201);
    const bool doL1 = (t <= 219);
    const bool doL2 = isA && (t >= 1);

    // ---- Phase 2 (waves 0-3): L2 for step t-1 ----
    if (doL2) {
      f32x4 acc2[4];
      #pragma unroll
      for (int ty = 0; ty < 4; ty++)
        acc2[ty] = (f32x4){b2r[ty], b2r[ty], b2r[ty], b2r[ty]};
      #pragma unroll
      for (int kc = 0; kc < 4; kc++) {
        const short8 fhi = *(const short8*)&Xc[c * X1S + kc * 32 + q * 8];
        #pragma unroll
        for (int ty = 0; ty < 4; ty++) {
          const short8 wf_ = *(const short8*)&W2F[(wv * 16 + ty * 4 + kc) * 512 + l * 8];
          acc2[ty] = mfma_(fhi, wf_, acc2[ty]);
        }
      }
      #pragma unroll
      for (int kc = 0; kc < 2; kc++) {
        const short8 hhi = *(const short8*)&Hprev[c * H2S + kc * 32 + q * 8];
        #pragma unroll
        for (int ty = 0; ty < 4; ty++)
          acc2[ty] = mfma_(hhi, w2h[ty][kc], acc2[ty]);
      }
      const int u = wv * 16 + c;
      #pragma unroll
      for (int r = 0; r < 4; r++) {
        float ig = sigm(acc2[0][r]);
        float fg = sigm(acc2[1][r]);
        float gg = tanh_(acc2[2][r]);
        float og = sigm(acc2[3][r]);
        float cn = fg * c2[r] + ig * gg;
        float hn = og * tanh_(cn);
        c2[r] = cn;
        Hdst[(q * 4 + r) * H2S + u] = f2bf(hn);
      }
    }

    // ---- x staging (waves 4-7): stage x(t+1), prefetch x(t+2) ----
    if (!isA) {
      const float xw = xreg; const bool dw = dreg;
      const int s2 = t + 2;
      dreg = false;
      if (s2 < 200) { xreg = xh[(bb + xr) * 3200 + s2 * 16 + xcc]; dreg = true; }
      else if (s2 < 220) {
        const int s = s2 - 200;
        if (xcc < 14)    { xreg = xfr[(bb + xr) * 280 + s * 14 + xcc]; dreg = true; }
        else if (s == 0) { xreg = xh[(bb + xr) * 3200 + 199 * 16 + xcc]; dreg = true; }
      }
      if (dw) Xn[xr * X1S + 128 + xcc] = f2bf(xw);
    }

    // ---- decoder head (waves 4,5 Wd; wave 4 Wf) ----
    if (dec) {
      __syncthreads();                 // #1: h2(t-1) visible
      if (wv == 4 || wv == 5) {
        const int ww = wv - 4;
        f32x4 accd = (f32x4){bdr, bdr, bdr, bdr};
        #pragma unroll
        for (int kc = 0; kc < 2; kc++) {
          const short8 ad  = *(const short8*)&Hdst[c * H2S + kc * 32 + q * 8];
          const short8 wdk = *(const short8*)&WdF[(ww * 2 + kc) * 512 + l * 8];
          accd = mfma_(ad, wdk, accd);
        }
        #pragma unroll
        for (int r = 0; r < 4; r++)
          DB[(q * 4 + r) * DBS + ww * 16 + c] = f2bf(fmaxf(accd[r], 0.f));
      }
      __syncthreads();                 // #2: d visible
      if (wv == 4) {
        const short8 ap  = *(const short8*)&DB[c * DBS + q * 8];
        const short8 wfv = *(const short8*)&WfF[l * 8];
        f32x4 accp = (f32x4){bfr, bfr, bfr, bfr};
        accp = mfma_(ap, wfv, accp);
        if (c < 2) {
          #pragma unroll
          for (int r = 0; r < 4; r++) {
            const int b = q * 4 + r;
            out[(bb + b) * 40 + (t - 201) * 2 + c] = accp[r];
            PREDV[b][c] = f2bf(accp[r]);
          }
        }
      }
      __syncthreads();                 // #3: pred visible
    }

    // ---- Phase 1 (all waves): L1(t) ----
    if (doL1) {
      f32x4 acc1[4];
      #pragma unroll
      for (int ty = 0; ty < 4; ty++)
        acc1[ty] = (f32x4){b1r[ty], b1r[ty], b1r[ty], b1r[ty]};
      #pragma unroll
      for (int kc = 0; kc < 4; kc++) {
        const short8 ahi = *(const short8*)&Xc[c * X1S + kc * 32 + q * 8];
        #pragma unroll
        for (int ty = 0; ty < 4; ty++)
          acc1[ty] = mfma_(ahi, w1h[ty][kc], acc1[ty]);
      }
      {
        short8 ax = *(const short8*)&Xc[c * X1S + 128 + q * 8];
        if (dec && q == 1) {           // pred feedback: features 14,15
          ax[6] = (short)PREDV[c][0];
          ax[7] = (short)PREDV[c][1];
        }
        #pragma unroll
        for (int ty = 0; ty < 4; ty++) {
          short8 wxv = (short8){0,0,0,0,0,0,0,0};
          if (q < 2)
            wxv = *(const short8*)&W1xF[(ty * 8 + wv) * 256 + l * 8];
          acc1[ty] = mfma_(ax, wxv, acc1[ty]);
        }
      }
      const int u = wv * 16 + c;
      #pragma unroll
      for (int r = 0; r < 4; r++) {
        float ig = sigm(acc1[0][r]);
        float fg = sigm(acc1[1][r]);
        float gg = tanh_(acc1[2][r]);
        float og = sigm(acc1[3][r]);
        float cn = fg * c1[r] + ig * gg;
        float hn = og * tanh_(cn);
        c1[r] = cn;
        Xn[(q * 4 + r) * X1S + u] = f2bf(hn);
      }
    }
    __syncthreads();                   // end: h1(t), h2(t-1), x(t+1) published
  }
}

extern "C" void kernel_launch(void* const* d_in, const int* in_sizes, int n_in,
                              void* d_out, int out_size, void* d_ws, size_t ws_size,
                              hipStream_t stream) {
  (void)in_sizes; (void)n_in; (void)out_size; (void)d_ws; (void)ws_size;
  spc_lstm<<<dim3(256), dim3(512), 0, stream>>>(
      (const float*)d_in[0],  (const float*)d_in[1],
      (const float*)d_in[2],  (const float*)d_in[3],
      (const float*)d_in[4],  (const float*)d_in[5],
      (const float*)d_in[6],  (const float*)d_in[7],
      (const float*)d_in[8],  (const float*)d_in[9],
      (const float*)d_in[10], (const float*)d_in[11],
      (const float*)d_in[12], (const float*)d_in[13],
      (const float*)d_in[14], (float*)d_out);
}

// Round 13
// 459.874 us; speedup vs baseline: 1.7091x; 1.0196x over previous
//
#include <hip/hip_runtime.h>

typedef unsigned short u16;
typedef unsigned int u32;

using short8 = __attribute__((ext_vector_type(8))) short;
using f32x4  = __attribute__((ext_vector_type(4))) float;
using float4v = __attribute__((ext_vector_type(4))) float;

#define LOG2E 1.44269504088896340736f

// X1 row (per batch): [h1 0:128 | pad] (u16)
#define X1S 136
// H2 row: [h2 0:64 | pad]
#define H2S 72
#define DBS 40
// XCH row stride: 8 steps * 40 + 8 pad (656 B: 16B-aligned, bank-stride 4)
#define XCS 328

__device__ __forceinline__ u16 f2bf(float f) {
  u32 u = __float_as_uint(f);
  return (u16)((u + 0x7FFFu + ((u >> 16) & 1u)) >> 16);
}
__device__ __forceinline__ float sigm(float x) {
  return __builtin_amdgcn_rcpf(1.0f + __builtin_amdgcn_exp2f(-LOG2E * x));
}
__device__ __forceinline__ float tanh_(float x) {
  return 1.0f - 2.0f * __builtin_amdgcn_rcpf(1.0f + __builtin_amdgcn_exp2f(2.0f * LOG2E * x));
}
__device__ __forceinline__ f32x4 mfma_(short8 a, short8 b, f32x4 c) {
  return __builtin_amdgcn_mfma_f32_16x16x32_bf16(a, b, c, 0, 0, 0);
}

// R13 = R12 (best: 437 us) minus hot-loop VALU overhead:
//  - W1xF full 512-entry tiles (zeros baked) -> no q<2 masks on x-MFMAs
//  - x staged in 8-step LDS chunks (XCH ring), loaded 1x/8 steps, coalesced
//  - pred feedback written directly into the XCH slot by the head
__global__ __launch_bounds__(512, 1) void spc_lstm(
    const float* __restrict__ xh,   const float* __restrict__ xfr,
    const float* __restrict__ Wih1, const float* __restrict__ Whh1,
    const float* __restrict__ bih1, const float* __restrict__ bhh1,
    const float* __restrict__ Wih2, const float* __restrict__ Whh2,
    const float* __restrict__ bih2, const float* __restrict__ bhh2,
    const float* __restrict__ Wd,   const float* __restrict__ bd,
    const float* __restrict__ Wf,   const float* __restrict__ bfv,
    const float* __restrict__ ob,   float* __restrict__ out)
{
  __shared__ __align__(16) u16 X1[2][16 * X1S];   //  8704 B
  __shared__ __align__(16) u16 H2B[2][16 * H2S];  //  4608 B
  __shared__ __align__(16) u16 DB[16 * DBS];      //  1280 B
  __shared__ __align__(16) u16 W1xF[32 * 512];    // 32768 B (zeros k>=16 baked)
  __shared__ __align__(16) u16 W2F[64 * 512];     // 65536 B
  __shared__ __align__(16) u16 WdF[4 * 512];      //  4096 B
  __shared__ __align__(16) u16 WfF[512];          //  1024 B
  __shared__ __align__(16) u16 XCH[2][16 * XCS];  // 20992 B x chunk ring
  // total ~135.8 KB

  const int tid = threadIdx.x;
  const int wv  = tid >> 6;          // 0..7
  const int l   = tid & 63;
  const int c   = l & 15;
  const int q   = l >> 4;
  const int bb  = blockIdx.x << 4;
  const bool isA = (wv < 4);         // waves 0-3: L1+L2; waves 4-7: L1 + chunks + head

  short8 w1h[4][4];                  // Whh1 frags (64 VGPR)
  short8 w2h[4][2];                  // A only: Whh2 frags (32 VGPR)
  float  b1r[4];
  float  b2r[4] = {0.f, 0.f, 0.f, 0.f};

  // ---- zero activation + chunk LDS ----
  for (int i = tid; i < 2 * 16 * X1S; i += 512) ((u16*)X1)[i] = 0;
  for (int i = tid; i < 2 * 16 * H2S; i += 512) ((u16*)H2B)[i] = 0;
  for (int i = tid; i < 16 * DBS; i += 512) DB[i] = 0;
  for (int i = tid; i < 2 * 16 * XCS; i += 512) ((u16*)XCH)[i] = 0;
  __syncthreads();

  // ---- weight LDS fills (fragment-linear: (k,n) -> ((k>>3)*16+n)*8 + (k&7)) ----
  for (int i = tid; i < 64 * 512; i += 512) {         // Wih2 tiles (ww, ty, kc)
    const int rid = i >> 9, e = i & 511, k = e >> 4, n = e & 15;
    const int ww = rid >> 4, ty = (rid >> 2) & 3, kc = rid & 3;
    const int g = ty * 64 + ww * 16 + n;
    W2F[rid * 512 + ((k >> 3) * 16 + n) * 8 + (k & 7)] = f2bf(Wih2[g * 128 + kc * 32 + k]);
  }
  for (int i = tid; i < 32 * 512; i += 512) {         // Wih1 x-frags FULL (zeros k>=16)
    const int T = i >> 9, e = i & 511, k = e >> 4, n = e & 15;
    const int ty = T >> 3, uv = T & 7;
    const int g = ty * 128 + uv * 16 + n;
    W1xF[T * 512 + ((k >> 3) * 16 + n) * 8 + (k & 7)] =
        (k < 16) ? f2bf(Wih1[g * 16 + k]) : (u16)0;
  }
  for (int i = tid; i < 4 * 512; i += 512) {          // Wd tiles (ww, kc2)
    const int tix = i >> 9, e = i & 511, k = e >> 4, n = e & 15;
    const int ww = tix >> 1, kc2 = tix & 1;
    WdF[tix * 512 + ((k >> 3) * 16 + n) * 8 + (k & 7)] =
        f2bf(Wd[(ww * 16 + n) * 64 + kc2 * 32 + k]);
  }
  {                                                   // Wf (zeros n>=2)
    const int k = tid >> 4, n = tid & 15;
    if (tid < 512)
      WfF[((k >> 3) * 16 + n) * 8 + (k & 7)] = (n < 2) ? f2bf(Wf[n * 32 + k]) : (u16)0;
  }

  // ---- chunk 0 load (B waves): steps 0-7 into XCH[0] ----
  if (!isA) {
    const int i0 = tid - 256;
    #pragma unroll
    for (int p = 0; p < 2; p++) {
      const int idx = i0 + p * 256;
      const int r = idx >> 5, rem = idx & 31, st = rem >> 2, hf = rem & 3;
      const float4v v = *(const float4v*)&xh[(bb + r) * 3200 + st * 16 + hf * 4];
      u16* d = &XCH[0][r * XCS + st * 40 + hf * 4];
      d[0] = f2bf(v[0]); d[1] = f2bf(v[1]); d[2] = f2bf(v[2]); d[3] = f2bf(v[3]);
    }
  }

  // ---- register weights / biases (wave wv owns L1 units wv*16+c) ----
  #pragma unroll
  for (int ty = 0; ty < 4; ty++) {
    const int g = ty * 128 + wv * 16 + c;
    b1r[ty] = bih1[g] + bhh1[g];
    #pragma unroll
    for (int kc = 0; kc < 4; kc++) {
      short8 v;
      #pragma unroll
      for (int j = 0; j < 8; j++)
        v[j] = (short)f2bf(Whh1[g * 128 + kc * 32 + q * 8 + j]);
      w1h[ty][kc] = v;
    }
  }
  if (isA) {
    #pragma unroll
    for (int ty = 0; ty < 4; ty++) {
      const int g2 = ty * 64 + wv * 16 + c;
      b2r[ty] = bih2[g2] + bhh2[g2];
      #pragma unroll
      for (int kc = 0; kc < 2; kc++) {
        short8 v;
        #pragma unroll
        for (int j = 0; j < 8; j++)
          v[j] = (short)f2bf(Whh2[g2 * 64 + kc * 32 + q * 8 + j]);
        w2h[ty][kc] = v;
      }
    }
  }
  const float bdr = (wv == 4 || wv == 5) ? bd[(wv - 4) * 16 + c] : 0.f;
  const float bfr = (wv == 4 && c < 2) ? (bfv[c] + ob[c]) : 0.f;

  f32x4 c1 = (f32x4){0,0,0,0};
  f32x4 c2 = (f32x4){0,0,0,0};
  __syncthreads();

  for (int t = 0; t <= 220; t++) {
    u16* Xc    = X1[t & 1];        // h1(t-1)
    u16* Xn    = X1[(t + 1) & 1];  // h1(t) dest
    u16* Hprev = H2B[t & 1];       // h2(t-2)
    u16* Hdst  = H2B[(t + 1) & 1]; // h2(t-1) dest
    const bool dec  = (t >= 201);
    const bool doL1 = (t <= 219);
    const bool doL2 = isA && (t >= 1);

    // ---- B: chunk loader, 1x per 8 steps (writes the OPPOSITE ring slot) ----
    if (!isA && (t & 7) == 0) {
      const int cm = (t >> 3) + 1;
      if (cm <= 27) {
        u16* dst = XCH[cm & 1];
        const int t0 = cm << 3;
        if (cm <= 24) {                    // pure-encoder chunk: coalesced float4
          const int i0 = tid - 256;
          #pragma unroll
          for (int p = 0; p < 2; p++) {
            const int idx = i0 + p * 256;
            const int r = idx >> 5, rem = idx & 31, st = rem >> 2, hf = rem & 3;
            const float4v v = *(const float4v*)&xh[(bb + r) * 3200 + (t0 + st) * 16 + hf * 4];
            u16* d = &dst[r * XCS + st * 40 + hf * 4];
            d[0] = f2bf(v[0]); d[1] = f2bf(v[1]); d[2] = f2bf(v[2]); d[3] = f2bf(v[3]);
          }
        } else {                           // decoder chunks 25-27: xfr feats 0..13
          for (int e = tid - 256; e < 16 * 8 * 14; e += 256) {
            const int r = e / 112, rem2 = e % 112, st = rem2 / 14, f = rem2 % 14;
            const int s8 = t0 + st;
            if (s8 < 220)
              dst[r * XCS + st * 40 + f] = f2bf(xfr[(bb + r) * 280 + (s8 - 200) * 14 + f]);
          }
          if (cm == 25) {                  // s=0 feats 14,15 from x_history[..,199,..]
            const int e = tid - 256;
            if (e < 32) {
              const int r = e >> 1, f = 14 + (e & 1);
              dst[r * XCS + f] = f2bf(xh[(bb + r) * 3200 + 199 * 16 + f]);
            }
          }
        }
      }
    }

    // ---- A: L2 for step t-1 ----
    if (doL2) {
      f32x4 acc2[4];
      #pragma unroll
      for (int ty = 0; ty < 4; ty++)
        acc2[ty] = (f32x4){b2r[ty], b2r[ty], b2r[ty], b2r[ty]};
      #pragma unroll
      for (int kc = 0; kc < 4; kc++) {
        const short8 fhi = *(const short8*)&Xc[c * X1S + kc * 32 + q * 8];
        #pragma unroll
        for (int ty = 0; ty < 4; ty++) {
          const short8 wf_ = *(const short8*)&W2F[(wv * 16 + ty * 4 + kc) * 512 + l * 8];
          acc2[ty] = mfma_(fhi, wf_, acc2[ty]);
        }
      }
      #pragma unroll
      for (int kc = 0; kc < 2; kc++) {
        const short8 hhi = *(const short8*)&Hprev[c * H2S + kc * 32 + q * 8];
        #pragma unroll
        for (int ty = 0; ty < 4; ty++)
          acc2[ty] = mfma_(hhi, w2h[ty][kc], acc2[ty]);
      }
      const int u = wv * 16 + c;
      #pragma unroll
      for (int r = 0; r < 4; r++) {
        float ig = sigm(acc2[0][r]);
        float fg = sigm(acc2[1][r]);
        float gg = tanh_(acc2[2][r]);
        float og = sigm(acc2[3][r]);
        float cn = fg * c2[r] + ig * gg;
        float hn = og * tanh_(cn);
        c2[r] = cn;
        Hdst[(q * 4 + r) * H2S + u] = f2bf(hn);
      }
    }

    // ---- decoder head ----
    if (dec) {
      __syncthreads();                 // #1: h2(t-1) visible
      if (wv == 4 || wv == 5) {
        const int ww = wv - 4;
        f32x4 accd = (f32x4){bdr, bdr, bdr, bdr};
        #pragma unroll
        for (int kc = 0; kc < 2; kc++) {
          const short8 ad  = *(const short8*)&Hdst[c * H2S + kc * 32 + q * 8];
          const short8 wdk = *(const short8*)&WdF[(ww * 2 + kc) * 512 + l * 8];
          accd = mfma_(ad, wdk, accd);
        }
        #pragma unroll
        for (int r = 0; r < 4; r++)
          DB[(q * 4 + r) * DBS + ww * 16 + c] = f2bf(fmaxf(accd[r], 0.f));
      }
      __syncthreads();                 // #2: d visible
      if (wv == 4) {
        const short8 ap  = *(const short8*)&DB[c * DBS + q * 8];
        const short8 wfv = *(const short8*)&WfF[l * 8];
        f32x4 accp = (f32x4){bfr, bfr, bfr, bfr};
        accp = mfma_(ap, wfv, accp);
        if (c < 2) {
          u16* slot = &XCH[(t >> 3) & 1][0];
          #pragma unroll
          for (int r = 0; r < 4; r++) {
            const int b = q * 4 + r;
            out[(bb + b) * 40 + (t - 201) * 2 + c] = accp[r];
            slot[b * XCS + (t & 7) * 40 + 14 + c] = f2bf(accp[r]);  // pred -> x(t)
          }
        }
      }
      __syncthreads();                 // #3: pred in XCH visible
    }

    // ---- L1(t), all waves (x path identical for enc/dec) ----
    if (doL1) {
      f32x4 acc1[4];
      #pragma unroll
      for (int ty = 0; ty < 4; ty++)
        acc1[ty] = (f32x4){b1r[ty], b1r[ty], b1r[ty], b1r[ty]};
      #pragma unroll
      for (int kc = 0; kc < 4; kc++) {
        const short8 ahi = *(const short8*)&Xc[c * X1S + kc * 32 + q * 8];
        #pragma unroll
        for (int ty = 0; ty < 4; ty++)
          acc1[ty] = mfma_(ahi, w1h[ty][kc], acc1[ty]);
      }
      {
        const short8 ax =
            *(const short8*)&XCH[(t >> 3) & 1][c * XCS + (t & 7) * 40 + q * 8];
        #pragma unroll
        for (int ty = 0; ty < 4; ty++) {
          const short8 wxv = *(const short8*)&W1xF[(ty * 8 + wv) * 512 + l * 8];
          acc1[ty] = mfma_(ax, wxv, acc1[ty]);
        }
      }
      const int u = wv * 16 + c;
      #pragma unroll
      for (int r = 0; r < 4; r++) {
        float ig = sigm(acc1[0][r]);
        float fg = sigm(acc1[1][r]);
        float gg = tanh_(acc1[2][r]);
        float og = sigm(acc1[3][r]);
        float cn = fg * c1[r] + ig * gg;
        float hn = og * tanh_(cn);
        c1[r] = cn;
        Xn[(q * 4 + r) * X1S + u] = f2bf(hn);
      }
    }
    __syncthreads();                   // end: h1(t), h2(t-1), chunk data published
  }
}

extern "C" void kernel_launch(void* const* d_in, const int* in_sizes, int n_in,
                              void* d_out, int out_size, void* d_ws, size_t ws_size,
                              hipStream_t stream) {
  (void)in_sizes; (void)n_in; (void)out_size; (void)d_ws; (void)ws_size;
  spc_lstm<<<dim3(256), dim3(512), 0, stream>>>(
      (const float*)d_in[0],  (const float*)d_in[1],
      (const float*)d_in[2],  (const float*)d_in[3],
      (const float*)d_in[4],  (const float*)d_in[5],
      (const float*)d_in[6],  (const float*)d_in[7],
      (const float*)d_in[8],  (const float*)d_in[9],
      (const float*)d_in[10], (const float*)d_in[11],
      (const float*)d_in[12], (const float*)d_in[13],
      (const float*)d_in[14], (float*)d_out);
}